// Round 2
// baseline (17104.143 us; speedup 1.0000x reference)
//
#include <hip/hip_runtime.h>
#include <hip/hip_bf16.h>
#include <math.h>

#define T_ 128
#define B_ 256
#define BP 512     // 2B (party batch)
#define D_ 1024
#define H_ 150
#define G_ 600     // 4H
#define O_ 300     // 2H
#define KP 152     // Whh K padded to multiple of 4 (rows 150,151 zeroed)

// ---------------- workspace layout (4-byte words from ws base), total ~291 MB ----
static const size_t INV_OFF   = 0;                                   // int[128*512]
static const size_t WIHT0_OFF = 65536;                               // 4 slots x 1024*600
static const size_t WIHT1_OFF = WIHT0_OFF + 4ull * 1024 * 600;       // 4 slots x 300*600
static const size_t WHHT_OFF  = WIHT1_OFF + 4ull * 300 * 600;        // 8 slots x KP*600
static const size_t XWA_OFF   = WHHT_OFF + 8ull * KP * 600;          // 32768*600
static const size_t XWB_OFF   = XWA_OFF + 32768ull * 600;            // 32768*600
static const size_t HRNN_OFF  = XWB_OFF + 32768ull * 600;            // 32768*300
static const size_t HPR_OFF   = HRNN_OFF + 32768ull * 300;           // 65536*300
// END = HPR_OFF + 65536*300 = 72,785,536 words = 291.1 MB

// ---------------- inverse map: (pos p, party row) -> dialogue row or -1 ----------
__global__ void k_pos(const int* __restrict__ qmask, int* __restrict__ inv) {
    int b = threadIdx.x;   // 256 threads, one per batch column
    // clear this thread's two party columns across all positions (no races)
    for (int p = 0; p < T_; ++p) {
        inv[p * BP + b] = -1;
        inv[p * BP + B_ + b] = -1;
    }
    int c0 = 0, c1 = 0;
    for (int t = 0; t < T_; ++t) {
        int s = qmask[(t * B_ + b) * 2 + 1];   // one-hot -> speaker id
        int p = s ? c1++ : c0++;
        inv[p * BP + s * B_ + b] = t * B_ + b;
    }
}

// ---------------- transpose W[g][k] -> WT[k][g], zero-pad rows k in [K,Kpad) -----
__global__ void k_transpose(const float* __restrict__ src, float* __restrict__ dst,
                            int K, int Kpad) {
    int idx = blockIdx.x * 256 + threadIdx.x;
    int total = Kpad * G_;
    if (idx < total) {
        int k = idx / G_, g = idx - k * G_;
        dst[idx] = (k < K) ? src[(size_t)g * K + k] : 0.f;
    }
}

// ---------------- fp32 GEMM: C[M,600] = A[M,K] @ BT[K,600] + bias ----------------
// tile 128(M) x 64(N) x 16(K); 256 threads; 8x4 micro-tile. M % 128 == 0.
__global__ __launch_bounds__(256) void k_gemm(const float* __restrict__ A,
                                              const float* __restrict__ BT,
                                              const float* __restrict__ bias,
                                              float* __restrict__ C,
                                              int M, int K) {
    __shared__ float As[16][137];   // As[k][m]
    __shared__ float Bs[16][65];    // Bs[k][n]
    int n0 = blockIdx.x * 64, m0 = blockIdx.y * 128;
    int tid = threadIdx.x;
    int tx = tid & 15, ty = tid >> 4;           // tx: N (x4), ty: M (x8)
    int ar = tid >> 2, ac = (tid & 3) * 4;      // A-load: row, k-col
    int kr = tid >> 4, nc = (tid & 15) * 4;     // B-load: k-row, n-col
    float acc[8][4];
#pragma unroll
    for (int i = 0; i < 8; ++i)
#pragma unroll
        for (int j = 0; j < 4; ++j) acc[i][j] = 0.f;

    for (int k0 = 0; k0 < K; k0 += 16) {
#pragma unroll
        for (int half = 0; half < 2; ++half) {
            int m = m0 + ar + half * 64;
#pragma unroll
            for (int i = 0; i < 4; ++i) {
                int k = k0 + ac + i;
                As[ac + i][ar + half * 64] = (k < K) ? A[(size_t)m * K + k] : 0.f;
            }
        }
#pragma unroll
        for (int i = 0; i < 4; ++i) {
            int k = k0 + kr, n = n0 + nc + i;
            Bs[kr][nc + i] = (k < K && n < G_) ? BT[(size_t)k * G_ + n] : 0.f;
        }
        __syncthreads();
#pragma unroll
        for (int kk = 0; kk < 16; ++kk) {
            float a[8], b[4];
#pragma unroll
            for (int i = 0; i < 8; ++i) a[i] = As[kk][ty * 8 + i];
#pragma unroll
            for (int j = 0; j < 4; ++j) b[j] = Bs[kk][tx * 4 + j];
#pragma unroll
            for (int i = 0; i < 8; ++i)
#pragma unroll
                for (int j = 0; j < 4; ++j) acc[i][j] += a[i] * b[j];
        }
        __syncthreads();
    }
#pragma unroll
    for (int i = 0; i < 8; ++i) {
        int m = m0 + ty * 8 + i;
#pragma unroll
        for (int j = 0; j < 4; ++j) {
            int n = n0 + tx * 4 + j;
            if (n < G_) C[(size_t)m * G_ + n] = acc[i][j] + bias[n];
        }
    }
}

// ---------------- LSTM scan: each block owns 8 rows over all 128 steps -----------
struct Combo {
    const float* xw;      // gate pre-acts (minus recurrent part): rows per mode
    const float* whhT;    // [KP][600], rows >=150 are zero
    const float* bias;    // [600] fallback for gatherIn padding rows
    const int*   inv;     // [128*512] (pos,partyRow) -> dialogRow | -1
    const float* addSrc;  // gatherOut: emotions base [32768*300]
    const float* umask;   // gatherOut: [32768]
    float*       out;     // output base
    int Bn;               // rows per time step (256 or 512)
    int colOff;           // 0 (fwd) or 150 (bwd)
    int bwd;
    int gatherIn;         // xw indexed via inv (dialogue order), bias on padding
    int gatherOut;        // out = (addSrc + h) * umask at inv row; skip padding
};
struct ScanArgs { Combo c[2]; int blkStart[3]; };

__global__ __launch_bounds__(256) void k_scan(ScanArgs args) {
    int bx = blockIdx.x;
    int ci = (bx >= args.blkStart[1]) ? 1 : 0;
    Combo cb = args.c[ci];
    int row0 = (bx - args.blkStart[ci]) * 8;

    __shared__ float hs[8][KP];
    __shared__ float cs[8][KP];
    __shared__ float gs[8][608];
    int tid = threadIdx.x;
    for (int idx = tid; idx < 8 * KP; idx += 256) {
        ((float*)hs)[idx] = 0.f;
        ((float*)cs)[idx] = 0.f;
    }
    __syncthreads();

    int c0 = tid, c1 = tid + 256, c2 = tid + 512;
    bool h2 = (c2 < G_);
    for (int s = 0; s < T_; ++s) {
        int t = cb.bwd ? (T_ - 1 - s) : s;
        float a0[8], a1[8], a2[8];
#pragma unroll
        for (int r = 0; r < 8; ++r) {
            const float* xr;
            if (cb.gatherIn) {
                int g = cb.inv[t * cb.Bn + row0 + r];   // broadcast load
                xr = (g >= 0) ? cb.xw + (size_t)g * G_ : cb.bias;
            } else {
                xr = cb.xw + ((size_t)t * cb.Bn + row0 + r) * G_;
            }
            a0[r] = xr[c0];
            a1[r] = xr[c1];
            a2[r] = h2 ? xr[c2] : 0.f;
        }
        // recurrent MAC: gates += h @ WhhT  (K padded to 152, zero rows harmless)
        for (int k4 = 0; k4 < KP; k4 += 4) {
            float4 hv[8];
#pragma unroll
            for (int r = 0; r < 8; ++r) hv[r] = *(const float4*)&hs[r][k4];
#pragma unroll
            for (int kk = 0; kk < 4; ++kk) {
                const float* wrow = cb.whhT + (size_t)(k4 + kk) * G_;
                float w0 = wrow[c0];
                float w1 = wrow[c1];
                float w2 = h2 ? wrow[c2] : 0.f;
#pragma unroll
                for (int r = 0; r < 8; ++r) {
                    float h = (&hv[r].x)[kk];
                    a0[r] += h * w0;
                    a1[r] += h * w1;
                    a2[r] += h * w2;
                }
            }
        }
#pragma unroll
        for (int r = 0; r < 8; ++r) {
            gs[r][c0] = a0[r];
            gs[r][c1] = a1[r];
            if (h2) gs[r][c2] = a2[r];
        }
        __syncthreads();
        // gate combine + state update + output
        for (int idx = tid; idx < 8 * H_; idx += 256) {
            int r = idx / H_, j = idx - r * H_;
            float gi = gs[r][j], gf = gs[r][H_ + j], gg = gs[r][2 * H_ + j], go = gs[r][3 * H_ + j];
            float ii = 1.f / (1.f + expf(-gi));
            float ff = 1.f / (1.f + expf(-gf));
            float oo = 1.f / (1.f + expf(-go));
            float cc = ff * cs[r][j] + ii * tanhf(gg);
            float hh = oo * tanhf(cc);
            cs[r][j] = cc;
            hs[r][j] = hh;
            if (cb.gatherOut) {
                int g = cb.inv[t * cb.Bn + row0 + r];
                if (g >= 0) {
                    size_t o = (size_t)g * O_ + cb.colOff + j;
                    cb.out[o] = (cb.addSrc[o] + hh) * cb.umask[g];
                }
            } else {
                cb.out[((size_t)t * cb.Bn + row0 + r) * O_ + cb.colOff + j] = hh;
            }
        }
        __syncthreads();
    }
}

extern "C" void kernel_launch(void* const* d_in, const int* in_sizes, int n_in,
                              void* d_out, int out_size, void* d_ws, size_t ws_size,
                              hipStream_t stream) {
    const float* U        = (const float*)d_in[0];
    const int*   qmask    = (const int*)d_in[1];
    const float* umask    = (const float*)d_in[2];
    const float* rnn_Wih0 = (const float*)d_in[4];
    const float* rnn_Whh0 = (const float*)d_in[5];
    const float* rnn_b0   = (const float*)d_in[6];
    const float* rnn_Wih1 = (const float*)d_in[7];
    const float* rnn_Whh1 = (const float*)d_in[8];
    const float* rnn_b1   = (const float*)d_in[9];
    const float* pr_Wih0  = (const float*)d_in[10];
    const float* pr_Whh0  = (const float*)d_in[11];
    const float* pr_b0    = (const float*)d_in[12];
    const float* pr_Wih1  = (const float*)d_in[13];
    const float* pr_Whh1  = (const float*)d_in[14];
    const float* pr_b1    = (const float*)d_in[15];

    float* ws   = (float*)d_ws;
    int*   inv  = (int*)d_ws + INV_OFF;
    float* wihT0 = ws + WIHT0_OFF;   // slots: rnn-d0, rnn-d1, pr-d0, pr-d1
    float* wihT1 = ws + WIHT1_OFF;   // same slot order
    float* whhT  = ws + WHHT_OFF;    // slots: rnn0 d0,d1; pr0 d0,d1; rnn1 d0,d1; pr1 d0,d1
    float* xwA   = ws + XWA_OFF;
    float* xwB   = ws + XWB_OFF;
    float* h_rnn = ws + HRNN_OFF;
    float* h_pr  = ws + HPR_OFF;

    const size_t W0S = 1024ull * 600, W1S = 300ull * 600, WHS = (size_t)KP * 600;

    // 1. inverse map
    k_pos<<<dim3(1), dim3(256), 0, stream>>>(qmask, inv);

    // 2. weight transposes
    auto TP = [&](const float* src, float* dst, int K, int Kpad) {
        int total = Kpad * G_;
        k_transpose<<<dim3((total + 255) / 256), dim3(256), 0, stream>>>(src, dst, K, Kpad);
    };
    for (int d = 0; d < 2; ++d) {
        TP(rnn_Wih0 + (size_t)d * G_ * D_, wihT0 + (0 + d) * W0S, D_, D_);
        TP(pr_Wih0  + (size_t)d * G_ * D_, wihT0 + (2 + d) * W0S, D_, D_);
        TP(rnn_Wih1 + (size_t)d * G_ * O_, wihT1 + (0 + d) * W1S, O_, O_);
        TP(pr_Wih1  + (size_t)d * G_ * O_, wihT1 + (2 + d) * W1S, O_, O_);
        TP(rnn_Whh0 + (size_t)d * G_ * H_, whhT + (0 + d) * WHS, H_, KP);
        TP(pr_Whh0  + (size_t)d * G_ * H_, whhT + (2 + d) * WHS, H_, KP);
        TP(rnn_Whh1 + (size_t)d * G_ * H_, whhT + (4 + d) * WHS, H_, KP);
        TP(pr_Whh1  + (size_t)d * G_ * H_, whhT + (6 + d) * WHS, H_, KP);
    }

    dim3 blk(256);
    dim3 g32k(10, 256);    // M = 32768
    dim3 g64k(10, 512);    // M = 65536

    Combo cz = {};  // zero template

    // ---------------- layer 0: per direction -> h_rnn / h_pr ----------------
    for (int d = 0; d < 2; ++d) {
        k_gemm<<<g32k, blk, 0, stream>>>(U, wihT0 + (0 + d) * W0S, rnn_b0 + d * G_, xwA, 32768, D_);
        k_gemm<<<g32k, blk, 0, stream>>>(U, wihT0 + (2 + d) * W0S, pr_b0 + d * G_, xwB, 32768, D_);
        ScanArgs sa;
        sa.c[0] = cz;
        sa.c[0].xw = xwA; sa.c[0].whhT = whhT + (0 + d) * WHS;
        sa.c[0].out = h_rnn; sa.c[0].Bn = B_; sa.c[0].colOff = d * H_; sa.c[0].bwd = d;
        sa.c[1] = cz;
        sa.c[1].xw = xwB; sa.c[1].whhT = whhT + (2 + d) * WHS;
        sa.c[1].bias = pr_b0 + d * G_; sa.c[1].inv = inv;
        sa.c[1].out = h_pr; sa.c[1].Bn = BP; sa.c[1].colOff = d * H_; sa.c[1].bwd = d;
        sa.c[1].gatherIn = 1;
        sa.blkStart[0] = 0; sa.blkStart[1] = 32; sa.blkStart[2] = 96;
        k_scan<<<dim3(96), blk, 0, stream>>>(sa);
    }

    // ---------------- layer 1 rnn: both dirs, then fused scan (in-place) ----
    k_gemm<<<g32k, blk, 0, stream>>>(h_rnn, wihT1 + 0 * W1S, rnn_b1 + 0 * G_, xwA, 32768, O_);
    k_gemm<<<g32k, blk, 0, stream>>>(h_rnn, wihT1 + 1 * W1S, rnn_b1 + 1 * G_, xwB, 32768, O_);
    {
        ScanArgs sa;
        sa.c[0] = cz;
        sa.c[0].xw = xwA; sa.c[0].whhT = whhT + 4 * WHS;
        sa.c[0].out = h_rnn; sa.c[0].Bn = B_; sa.c[0].colOff = 0; sa.c[0].bwd = 0;
        sa.c[1] = cz;
        sa.c[1].xw = xwB; sa.c[1].whhT = whhT + 5 * WHS;
        sa.c[1].out = h_rnn; sa.c[1].Bn = B_; sa.c[1].colOff = H_; sa.c[1].bwd = 1;
        sa.blkStart[0] = 0; sa.blkStart[1] = 32; sa.blkStart[2] = 64;
        k_scan<<<dim3(64), blk, 0, stream>>>(sa);
    }

    // ---------------- layer 1 pr: per direction, fused final into d_out -----
    for (int d = 0; d < 2; ++d) {
        // xwA and xwB are adjacent => one contiguous 65536-row buffer
        k_gemm<<<g64k, blk, 0, stream>>>(h_pr, wihT1 + (2 + d) * W1S, pr_b1 + d * G_, xwA, 65536, O_);
        ScanArgs sa;
        sa.c[0] = cz;
        sa.c[0].xw = xwA; sa.c[0].whhT = whhT + (6 + d) * WHS;
        sa.c[0].inv = inv; sa.c[0].addSrc = h_rnn; sa.c[0].umask = umask;
        sa.c[0].out = (float*)d_out; sa.c[0].Bn = BP; sa.c[0].colOff = d * H_; sa.c[0].bwd = d;
        sa.c[0].gatherOut = 1;
        sa.c[1] = sa.c[0];
        sa.blkStart[0] = 0; sa.blkStart[1] = 64; sa.blkStart[2] = 64;
        k_scan<<<dim3(64), blk, 0, stream>>>(sa);
    }
}

// Round 3
// 17003.094 us; speedup vs baseline: 1.0059x; 1.0059x over previous
//
#include <hip/hip_runtime.h>
#include <hip/hip_bf16.h>
#include <math.h>

#define T_ 128
#define B_ 256
#define BP 512     // 2B (party batch)
#define D_ 1024
#define H_ 150
#define G_ 600     // 4H
#define O_ 300     // 2H
#define KPAD 156   // Whh K padded to mult of 4 (rows 150..155 zero)
#define KCH 39     // KPAD/4 chunks
#define ROWS 8     // batch rows per scan block

typedef float v2f __attribute__((ext_vector_type(2)));

// ---------------- workspace layout (4-byte words) ----------------
static const size_t INV_OFF   = 0;                                  // int[128*512]
static const size_t WIHT0_OFF = 65536;                              // 4 x 1024*600
static const size_t WIHT1_OFF = WIHT0_OFF + 4ull * 1024 * 600;      // 4 x 300*600
static const size_t WHHT_OFF  = WIHT1_OFF + 4ull * 300 * 600;       // 8 x KPAD*600
static const size_t XW_OFF    = WHHT_OFF + 8ull * KPAD * 600;       // 2 or 4 slots x 32768*600
static const size_t XSLOT     = 32768ull * 600;                     // 19,660,800 words

static size_t hrnn_off(int nslots) { return XW_OFF + (size_t)nslots * XSLOT; }
static size_t hpr_off(int nslots)  { return hrnn_off(nslots) + 32768ull * 300; }
static size_t total_words(int nslots) { return hpr_off(nslots) + 65536ull * 300; }

// ---------------- fast transcendentals ----------------
__device__ __forceinline__ float fsig(float x) {
    return __builtin_amdgcn_rcpf(1.f + __expf(-x));
}
__device__ __forceinline__ float ftanh(float x) {
    float xc = fminf(fmaxf(x, -15.f), 15.f);
    float e = __expf(-2.f * xc);
    return (1.f - e) * __builtin_amdgcn_rcpf(1.f + e);
}

// ---------------- inverse map: (pos p, party row) -> dialogue row or -1 ----------
__global__ void k_pos(const int* __restrict__ qmask, int* __restrict__ inv) {
    int b = threadIdx.x;   // 256 threads, one per batch column
    for (int p = 0; p < T_; ++p) {
        inv[p * BP + b] = -1;
        inv[p * BP + B_ + b] = -1;
    }
    int c0 = 0, c1 = 0;
    for (int t = 0; t < T_; ++t) {
        int s = qmask[(t * B_ + b) * 2 + 1];
        int p = s ? c1++ : c0++;
        inv[p * BP + s * B_ + b] = t * B_ + b;
    }
}

// ---------------- transpose W[g][k] -> WT[k][g], zero-pad rows k in [K,Kpad) -----
__global__ void k_transpose(const float* __restrict__ src, float* __restrict__ dst,
                            int K, int Kpad) {
    int idx = blockIdx.x * 256 + threadIdx.x;
    int total = Kpad * G_;
    if (idx < total) {
        int k = idx / G_, g = idx - k * G_;
        dst[idx] = (k < K) ? src[(size_t)g * K + k] : 0.f;
    }
}

// ---------------- fp32 GEMM: C[M,600] = A[M,K] @ BT[K,600] + bias ----------------
// tile 128(M) x 64(N) x 16(K); 256 threads; 8x4 micro-tile. M % 128 == 0.
__global__ __launch_bounds__(256) void k_gemm(const float* __restrict__ A,
                                              const float* __restrict__ BT,
                                              const float* __restrict__ bias,
                                              float* __restrict__ C,
                                              int M, int K) {
    __shared__ __align__(16) float As[16][136];   // As[k][m], 136%4==0 for b128 reads
    __shared__ __align__(16) float Bs[16][68];    // Bs[k][n]
    int n0 = blockIdx.x * 64, m0 = blockIdx.y * 128;
    int tid = threadIdx.x;
    int tx = tid & 15, ty = tid >> 4;
    int ar = tid >> 2, ac = (tid & 3) * 4;
    int kr = tid >> 4, nc = (tid & 15) * 4;
    float acc[8][4];
#pragma unroll
    for (int i = 0; i < 8; ++i)
#pragma unroll
        for (int j = 0; j < 4; ++j) acc[i][j] = 0.f;

    for (int k0 = 0; k0 < K; k0 += 16) {
        bool fullK = (k0 + 16 <= K);
#pragma unroll
        for (int half = 0; half < 2; ++half) {
            int m = m0 + ar + half * 64;
            const float* ap = A + (size_t)m * K + k0 + ac;
            if (fullK) {
                float4 v = *(const float4*)ap;
                As[ac + 0][ar + half * 64] = v.x;
                As[ac + 1][ar + half * 64] = v.y;
                As[ac + 2][ar + half * 64] = v.z;
                As[ac + 3][ar + half * 64] = v.w;
            } else {
#pragma unroll
                for (int i = 0; i < 4; ++i) {
                    int k = k0 + ac + i;
                    As[ac + i][ar + half * 64] = (k < K) ? ap[i] : 0.f;
                }
            }
        }
        {
            int k = k0 + kr, n = n0 + nc;
            if (fullK && n + 3 < G_) {
                float4 v = *(const float4*)(BT + (size_t)k * G_ + n);
                Bs[kr][nc + 0] = v.x; Bs[kr][nc + 1] = v.y;
                Bs[kr][nc + 2] = v.z; Bs[kr][nc + 3] = v.w;
            } else {
#pragma unroll
                for (int i = 0; i < 4; ++i) {
                    int nn = n + i;
                    Bs[kr][nc + i] = (k < K && nn < G_) ? BT[(size_t)k * G_ + nn] : 0.f;
                }
            }
        }
        __syncthreads();
#pragma unroll
        for (int kk = 0; kk < 16; ++kk) {
            float4 a0 = *(const float4*)&As[kk][ty * 8];
            float4 a1 = *(const float4*)&As[kk][ty * 8 + 4];
            float4 b  = *(const float4*)&Bs[kk][tx * 4];
            const float* af = (const float*)&a0;
            const float* af2 = (const float*)&a1;
            const float* bf = (const float*)&b;
#pragma unroll
            for (int i = 0; i < 4; ++i)
#pragma unroll
                for (int j = 0; j < 4; ++j) {
                    acc[i][j] += af[i] * bf[j];
                    acc[4 + i][j] += af2[i] * bf[j];
                }
        }
        __syncthreads();
    }
    int n = n0 + tx * 4;
    if (n + 3 < G_) {
        float4 bv = *(const float4*)(bias + n);
#pragma unroll
        for (int i = 0; i < 8; ++i) {
            int m = m0 + ty * 8 + i;
            float4 o;
            o.x = acc[i][0] + bv.x; o.y = acc[i][1] + bv.y;
            o.z = acc[i][2] + bv.z; o.w = acc[i][3] + bv.w;
            *(float4*)(C + (size_t)m * G_ + n) = o;
        }
    } else {
#pragma unroll
        for (int i = 0; i < 8; ++i) {
            int m = m0 + ty * 8 + i;
#pragma unroll
            for (int j = 0; j < 4; ++j)
                if (n + j < G_) C[(size_t)m * G_ + n + j] = acc[i][j] + bias[n + j];
        }
    }
}

// ---------------- LSTM scan ----------------
struct ScanArgs {
    const float* xw[4];
    const float* whhT[4];   // [KPAD][600]
    const float* bias[4];   // gatherIn padding fallback
    float*       out[4];
    const int*   inv;
    const float* addSrc;
    const float* umask;
    int Bn[4], colOff[4], bwd[4], gIn[4], gOut[4];
    int blkStart[5];
};

__global__ __launch_bounds__(320) void k_scan(ScanArgs args) {
    int bx = blockIdx.x;
    int ci = 0;
#pragma unroll
    for (int i = 1; i < 4; ++i)
        if (bx >= args.blkStart[i]) ci = i;
    const float* xw   = args.xw[ci];
    const float* whh  = args.whhT[ci];
    const float* bias = args.bias[ci];
    float* out        = args.out[ci];
    const int Bn = args.Bn[ci], colOff = args.colOff[ci], bwd = args.bwd[ci];
    const int gIn = args.gIn[ci], gOut = args.gOut[ci];
    int row0 = (bx - args.blkStart[ci]) * ROWS;

    __shared__ __align__(16) float hs[ROWS][KPAD];
    __shared__ __align__(16) float cs[ROWS][152];
    __shared__ __align__(16) float gs[ROWS][608];
    int tid = threadIdx.x;
    for (int i = tid; i < ROWS * KPAD; i += 320) ((float*)hs)[i] = 0.f;
    for (int i = tid; i < ROWS * 152; i += 320) ((float*)cs)[i] = 0.f;
    __syncthreads();

    int pr = tid < 300 ? tid : 299;   // column pair this thread owns (clamped dup)
    const int cp2 = 2 * pr;

    auto loadX = [&](int t, v2f* xb) {
#pragma unroll
        for (int r = 0; r < ROWS; ++r) {
            const float* xr;
            if (gIn) {
                int g = args.inv[t * Bn + row0 + r];
                xr = (g >= 0) ? xw + (size_t)g * G_ : bias;
            } else {
                xr = xw + ((size_t)t * Bn + row0 + r) * G_;
            }
            xb[r] = *(const v2f*)(xr + cp2);
        }
    };

    v2f xb[ROWS];
    loadX(bwd ? T_ - 1 : 0, xb);

    for (int s = 0; s < T_; ++s) {
        int t = bwd ? (T_ - 1 - s) : s;
        v2f a[ROWS];
#pragma unroll
        for (int r = 0; r < ROWS; ++r) a[r] = xb[r];
        if (s + 1 < T_) loadX(bwd ? (T_ - 2 - s) : (s + 1), xb);

        // fully-unrolled MAC: gates += h @ WhhT (KPAD rows, zero-padded tail)
#pragma unroll
        for (int c = 0; c < KCH; ++c) {
            v2f w[4];
#pragma unroll
            for (int kk = 0; kk < 4; ++kk)
                w[kk] = *(const v2f*)(whh + (size_t)(c * 4 + kk) * G_ + cp2);
            float4 hv[ROWS];
#pragma unroll
            for (int r = 0; r < ROWS; ++r) hv[r] = *(const float4*)&hs[r][c * 4];
#pragma unroll
            for (int kk = 0; kk < 4; ++kk) {
#pragma unroll
                for (int r = 0; r < ROWS; ++r) {
                    float h = ((const float*)&hv[r])[kk];
                    a[r] += w[kk] * h;   // v_pk_fma_f32
                }
            }
        }
        if (tid < 300) {
#pragma unroll
            for (int r = 0; r < ROWS; ++r) *(v2f*)&gs[r][cp2] = a[r];
        }
        __syncthreads();

        for (int i = tid; i < ROWS * H_; i += 320) {
            int r = i / H_, j = i - r * H_;
            float gi = gs[r][j], gf = gs[r][H_ + j], gg = gs[r][2 * H_ + j], go = gs[r][3 * H_ + j];
            float ii = fsig(gi), ff = fsig(gf), oo = fsig(go);
            float cc = ff * cs[r][j] + ii * ftanh(gg);
            float hh = oo * ftanh(cc);
            cs[r][j] = cc;
            hs[r][j] = hh;
            if (gOut) {
                int g = args.inv[t * Bn + row0 + r];
                if (g >= 0) {
                    size_t o = (size_t)g * O_ + colOff + j;
                    out[o] = (args.addSrc[o] + hh) * args.umask[g];
                }
            } else {
                out[((size_t)t * Bn + row0 + r) * O_ + colOff + j] = hh;
            }
        }
        __syncthreads();
    }
}

extern "C" void kernel_launch(void* const* d_in, const int* in_sizes, int n_in,
                              void* d_out, int out_size, void* d_ws, size_t ws_size,
                              hipStream_t stream) {
    const float* U        = (const float*)d_in[0];
    const int*   qmask    = (const int*)d_in[1];
    const float* umask    = (const float*)d_in[2];
    const float* rnn_Wih0 = (const float*)d_in[4];
    const float* rnn_Whh0 = (const float*)d_in[5];
    const float* rnn_b0   = (const float*)d_in[6];
    const float* rnn_Wih1 = (const float*)d_in[7];
    const float* rnn_Whh1 = (const float*)d_in[8];
    const float* rnn_b1   = (const float*)d_in[9];
    const float* pr_Wih0  = (const float*)d_in[10];
    const float* pr_Whh0  = (const float*)d_in[11];
    const float* pr_b0    = (const float*)d_in[12];
    const float* pr_Wih1  = (const float*)d_in[13];
    const float* pr_Whh1  = (const float*)d_in[14];
    const float* pr_b1    = (const float*)d_in[15];

    // adaptive layout: 4 xw slots (merged scans) if workspace allows, else 2
    const int nslots = (ws_size >= total_words(4) * 4ull) ? 4 : 2;

    float* ws    = (float*)d_ws;
    int*   inv   = (int*)d_ws + INV_OFF;
    float* wihT0 = ws + WIHT0_OFF;   // slots: rnn-d0, rnn-d1, pr-d0, pr-d1
    float* wihT1 = ws + WIHT1_OFF;
    float* whhT  = ws + WHHT_OFF;    // slots: rnn0 d0,d1; pr0 d0,d1; rnn1 d0,d1; pr1 d0,d1
    float* X0    = ws + XW_OFF;
    float* X1    = X0 + XSLOT;
    float* X2    = (nslots == 4) ? X1 + XSLOT : X0;   // big path only
    float* X3    = (nslots == 4) ? X2 + XSLOT : X1;
    float* h_rnn = ws + hrnn_off(nslots);
    float* h_pr  = ws + hpr_off(nslots);

    const size_t W0S = 1024ull * 600, W1S = 300ull * 600, WHS = (size_t)KPAD * 600;

    k_pos<<<dim3(1), dim3(256), 0, stream>>>(qmask, inv);

    auto TP = [&](const float* src, float* dst, int K, int Kpad) {
        int total = Kpad * G_;
        k_transpose<<<dim3((total + 255) / 256), dim3(256), 0, stream>>>(src, dst, K, Kpad);
    };
    for (int d = 0; d < 2; ++d) {
        TP(rnn_Wih0 + (size_t)d * G_ * D_, wihT0 + (0 + d) * W0S, D_, D_);
        TP(pr_Wih0  + (size_t)d * G_ * D_, wihT0 + (2 + d) * W0S, D_, D_);
        TP(rnn_Wih1 + (size_t)d * G_ * O_, wihT1 + (0 + d) * W1S, O_, O_);
        TP(pr_Wih1  + (size_t)d * G_ * O_, wihT1 + (2 + d) * W1S, O_, O_);
        TP(rnn_Whh0 + (size_t)d * G_ * H_, whhT + (0 + d) * WHS, H_, KPAD);
        TP(pr_Whh0  + (size_t)d * G_ * H_, whhT + (2 + d) * WHS, H_, KPAD);
        TP(rnn_Whh1 + (size_t)d * G_ * H_, whhT + (4 + d) * WHS, H_, KPAD);
        TP(pr_Whh1  + (size_t)d * G_ * H_, whhT + (6 + d) * WHS, H_, KPAD);
    }

    dim3 blk(256), sblk(320);
    dim3 g32k(10, 256);    // M = 32768
    dim3 g64k(10, 512);    // M = 65536

    ScanArgs z = {};
    auto setCombo = [&](ScanArgs& sa, int i, const float* xw, const float* wh,
                        const float* bi, float* o, int Bn, int co, int bw,
                        int gi, int go) {
        sa.xw[i] = xw; sa.whhT[i] = wh; sa.bias[i] = bi; sa.out[i] = o;
        sa.Bn[i] = Bn; sa.colOff[i] = co; sa.bwd[i] = bw; sa.gIn[i] = gi; sa.gOut[i] = go;
    };

    if (nslots == 4) {
        // ---- layer 0: all four GEMMs, one 192-block scan ----
        k_gemm<<<g32k, blk, 0, stream>>>(U, wihT0 + 0 * W0S, rnn_b0 + 0 * G_, X0, 32768, D_);
        k_gemm<<<g32k, blk, 0, stream>>>(U, wihT0 + 1 * W0S, rnn_b0 + 1 * G_, X1, 32768, D_);
        k_gemm<<<g32k, blk, 0, stream>>>(U, wihT0 + 2 * W0S, pr_b0 + 0 * G_, X2, 32768, D_);
        k_gemm<<<g32k, blk, 0, stream>>>(U, wihT0 + 3 * W0S, pr_b0 + 1 * G_, X3, 32768, D_);
        ScanArgs sa = z;
        sa.inv = inv;
        setCombo(sa, 0, X0, whhT + 0 * WHS, nullptr, h_rnn, B_, 0, 0, 0, 0);
        setCombo(sa, 1, X1, whhT + 1 * WHS, nullptr, h_rnn, B_, H_, 1, 0, 0);
        setCombo(sa, 2, X2, whhT + 2 * WHS, pr_b0 + 0 * G_, h_pr, BP, 0, 0, 1, 0);
        setCombo(sa, 3, X3, whhT + 3 * WHS, pr_b0 + 1 * G_, h_pr, BP, H_, 1, 1, 0);
        sa.blkStart[0] = 0; sa.blkStart[1] = 32; sa.blkStart[2] = 64;
        sa.blkStart[3] = 128; sa.blkStart[4] = 192;
        k_scan<<<dim3(192), sblk, 0, stream>>>(sa);

        // ---- layer 1 rnn GEMMs + pr-d0 GEMM, rnn scan ----
        k_gemm<<<g32k, blk, 0, stream>>>(h_rnn, wihT1 + 0 * W1S, rnn_b1 + 0 * G_, X0, 32768, O_);
        k_gemm<<<g32k, blk, 0, stream>>>(h_rnn, wihT1 + 1 * W1S, rnn_b1 + 1 * G_, X1, 32768, O_);
        k_gemm<<<g64k, blk, 0, stream>>>(h_pr, wihT1 + 2 * W1S, pr_b1 + 0 * G_, X2, 65536, O_);
        ScanArgs sr = z;
        sr.inv = inv;
        setCombo(sr, 0, X0, whhT + 4 * WHS, nullptr, h_rnn, B_, 0, 0, 0, 0);
        setCombo(sr, 1, X1, whhT + 5 * WHS, nullptr, h_rnn, B_, H_, 1, 0, 0);
        sr.blkStart[0] = 0; sr.blkStart[1] = 32; sr.blkStart[2] = 0x7fffffff;
        sr.blkStart[3] = 0x7fffffff; sr.blkStart[4] = 64;
        k_scan<<<dim3(64), sblk, 0, stream>>>(sr);

        // ---- layer 1 pr-d1 GEMM (into freed X0X1), then 128-block fused scan ----
        k_gemm<<<g64k, blk, 0, stream>>>(h_pr, wihT1 + 3 * W1S, pr_b1 + 1 * G_, X0, 65536, O_);
        ScanArgs sp = z;
        sp.inv = inv; sp.addSrc = h_rnn; sp.umask = umask;
        setCombo(sp, 0, X2, whhT + 6 * WHS, nullptr, (float*)d_out, BP, 0, 0, 0, 1);
        setCombo(sp, 1, X0, whhT + 7 * WHS, nullptr, (float*)d_out, BP, H_, 1, 0, 1);
        sp.blkStart[0] = 0; sp.blkStart[1] = 64; sp.blkStart[2] = 0x7fffffff;
        sp.blkStart[3] = 0x7fffffff; sp.blkStart[4] = 128;
        k_scan<<<dim3(128), sblk, 0, stream>>>(sp);
    } else {
        // ---- small-workspace phased path (round-2 structure) ----
        for (int d = 0; d < 2; ++d) {
            k_gemm<<<g32k, blk, 0, stream>>>(U, wihT0 + (0 + d) * W0S, rnn_b0 + d * G_, X0, 32768, D_);
            k_gemm<<<g32k, blk, 0, stream>>>(U, wihT0 + (2 + d) * W0S, pr_b0 + d * G_, X1, 32768, D_);
            ScanArgs sa = z;
            sa.inv = inv;
            setCombo(sa, 0, X0, whhT + (0 + d) * WHS, nullptr, h_rnn, B_, d * H_, d, 0, 0);
            setCombo(sa, 1, X1, whhT + (2 + d) * WHS, pr_b0 + d * G_, h_pr, BP, d * H_, d, 1, 0);
            sa.blkStart[0] = 0; sa.blkStart[1] = 32; sa.blkStart[2] = 0x7fffffff;
            sa.blkStart[3] = 0x7fffffff; sa.blkStart[4] = 96;
            k_scan<<<dim3(96), sblk, 0, stream>>>(sa);
        }
        k_gemm<<<g32k, blk, 0, stream>>>(h_rnn, wihT1 + 0 * W1S, rnn_b1 + 0 * G_, X0, 32768, O_);
        k_gemm<<<g32k, blk, 0, stream>>>(h_rnn, wihT1 + 1 * W1S, rnn_b1 + 1 * G_, X1, 32768, O_);
        {
            ScanArgs sr = z;
            sr.inv = inv;
            setCombo(sr, 0, X0, whhT + 4 * WHS, nullptr, h_rnn, B_, 0, 0, 0, 0);
            setCombo(sr, 1, X1, whhT + 5 * WHS, nullptr, h_rnn, B_, H_, 1, 0, 0);
            sr.blkStart[0] = 0; sr.blkStart[1] = 32; sr.blkStart[2] = 0x7fffffff;
            sr.blkStart[3] = 0x7fffffff; sr.blkStart[4] = 64;
            k_scan<<<dim3(64), sblk, 0, stream>>>(sr);
        }
        for (int d = 0; d < 2; ++d) {
            k_gemm<<<g64k, blk, 0, stream>>>(h_pr, wihT1 + (2 + d) * W1S, pr_b1 + d * G_, X0, 65536, O_);
            ScanArgs sp = z;
            sp.inv = inv; sp.addSrc = h_rnn; sp.umask = umask;
            setCombo(sp, 0, X0, whhT + (6 + d) * WHS, nullptr, (float*)d_out, BP, d * H_, d, 0, 1);
            sp.blkStart[0] = 0; sp.blkStart[1] = 0x7fffffff; sp.blkStart[2] = 0x7fffffff;
            sp.blkStart[3] = 0x7fffffff; sp.blkStart[4] = 64;
            k_scan<<<dim3(64), sblk, 0, stream>>>(sp);
        }
    }
}